// Round 1
// baseline (3524.889 us; speedup 1.0000x reference)
//
#include <hip/hip_runtime.h>

// Sizes (fixed by the problem)
// B=64 T=128 HID=512 LOC_EMB=256 TIM_EMB=64 UID_EMB=128 L_HIST=1024 G=4
// K_x = 320, K_attn = 448, N_gates = 1536, UID_SIZE = 5000

// ---------------- gather x = [emb_loc[loc], emb_tim[tim]] -> X[(t*64+b)][320] ----------------
__global__ void gather_x(const int* __restrict__ loc, const int* __restrict__ tim,
                         const float* __restrict__ eloc, const float* __restrict__ etim,
                         float* __restrict__ X) {
  int row = blockIdx.x;            // t*64 + b
  int t = row >> 6, b = row & 63;
  int tid = threadIdx.x;           // 64 threads
  float4* dst = (float4*)(X + (size_t)row * 320);
  int li = loc[b * 128 + t];
  dst[tid] = ((const float4*)(eloc + (size_t)li * 256))[tid];
  if (tid < 16) {
    int ti = tim[b * 128 + t];
    dst[64 + tid] = ((const float4*)(etim + (size_t)ti * 64))[tid];
  }
}

// ---------------- hist features: [loc(256) | tim(64) | uid_mean(128)] per (b, n) ----------------
__global__ void hist_feat(const int* __restrict__ hloc, const int* __restrict__ htim,
                          const int* __restrict__ huid,
                          const float* __restrict__ eloc, const float* __restrict__ etim,
                          const float* __restrict__ euid, float* __restrict__ histf) {
  int row = blockIdx.x;            // b*256 + n
  int b = row >> 8, n = row & 255;
  int tid = threadIdx.x;           // 64 threads
  int base = b * 1024 + (n << 2);  // history index of group start
  float4* dst = (float4*)(histf + (size_t)row * 448);
  {
    int li = hloc[base];
    dst[tid] = ((const float4*)(eloc + (size_t)li * 256))[tid];
  }
  if (tid < 16) {
    int ti = htim[base];
    dst[64 + tid] = ((const float4*)(etim + (size_t)ti * 64))[tid];
  }
  if (tid < 32) {
    const float4* u0 = (const float4*)(euid + (size_t)huid[base + 0] * 128);
    const float4* u1 = (const float4*)(euid + (size_t)huid[base + 1] * 128);
    const float4* u2 = (const float4*)(euid + (size_t)huid[base + 2] * 128);
    const float4* u3 = (const float4*)(euid + (size_t)huid[base + 3] * 128);
    float4 v0 = u0[tid], v1 = u1[tid], v2 = u2[tid], v3 = u3[tid];
    float4 o;
    o.x = 0.25f * (v0.x + v1.x + v2.x + v3.x);
    o.y = 0.25f * (v0.y + v1.y + v2.y + v3.y);
    o.z = 0.25f * (v0.z + v1.z + v2.z + v3.z);
    o.w = 0.25f * (v0.w + v1.w + v2.w + v3.w);
    dst[80 + tid] = o;
  }
}

// ---------------- fp32 tiled GEMM: C[m][n] = act(sum_k A[m][k]*B[n][k] + bias[n]) ----------------
// BM=BN=128, BK=16, 256 threads, 8x8 micro-tile. M,N multiples of 128; K multiple of 16.
template<bool TANH>
__global__ __launch_bounds__(256)
void gemm_bt(const float* __restrict__ A, const float* __restrict__ Bm,
             const float* __restrict__ bias, float* __restrict__ C,
             int M, int N, int K) {
  constexpr int BM = 128, BN = 128, BK = 16;
  __shared__ float As[BK][BM + 4];
  __shared__ float Bs[BK][BN + 4];
  const int tid = threadIdx.x;
  const int bm = blockIdx.y * BM, bn = blockIdx.x * BN;
  const int tm = (tid >> 4) << 3, tn = (tid & 15) << 3;
  const int lr = tid >> 2;             // 0..63
  const int lc = (tid & 3) << 2;       // 0,4,8,12
  const float* Ap0 = A + (size_t)(bm + lr) * K + lc;
  const float* Ap1 = A + (size_t)(bm + 64 + lr) * K + lc;
  const float* Bp0 = Bm + (size_t)(bn + lr) * K + lc;
  const float* Bp1 = Bm + (size_t)(bn + 64 + lr) * K + lc;
  float acc[8][8] = {};
  for (int k0 = 0; k0 < K; k0 += BK) {
    float4 a0 = *(const float4*)(Ap0 + k0);
    float4 a1 = *(const float4*)(Ap1 + k0);
    float4 b0 = *(const float4*)(Bp0 + k0);
    float4 b1 = *(const float4*)(Bp1 + k0);
    As[lc + 0][lr] = a0.x; As[lc + 1][lr] = a0.y; As[lc + 2][lr] = a0.z; As[lc + 3][lr] = a0.w;
    As[lc + 0][64 + lr] = a1.x; As[lc + 1][64 + lr] = a1.y; As[lc + 2][64 + lr] = a1.z; As[lc + 3][64 + lr] = a1.w;
    Bs[lc + 0][lr] = b0.x; Bs[lc + 1][lr] = b0.y; Bs[lc + 2][lr] = b0.z; Bs[lc + 3][lr] = b0.w;
    Bs[lc + 0][64 + lr] = b1.x; Bs[lc + 1][64 + lr] = b1.y; Bs[lc + 2][64 + lr] = b1.z; Bs[lc + 3][64 + lr] = b1.w;
    __syncthreads();
#pragma unroll
    for (int kk = 0; kk < BK; ++kk) {
      float a[8], bv[8];
      *(float4*)&a[0]  = *(const float4*)&As[kk][tm];
      *(float4*)&a[4]  = *(const float4*)&As[kk][tm + 4];
      *(float4*)&bv[0] = *(const float4*)&Bs[kk][tn];
      *(float4*)&bv[4] = *(const float4*)&Bs[kk][tn + 4];
#pragma unroll
      for (int i = 0; i < 8; ++i)
#pragma unroll
        for (int j = 0; j < 8; ++j)
          acc[i][j] += a[i] * bv[j];
    }
    __syncthreads();
  }
#pragma unroll
  for (int i = 0; i < 8; ++i) {
    float* crow = C + (size_t)(bm + tm + i) * N + bn + tn;
#pragma unroll
    for (int j = 0; j < 8; ++j) {
      float v = acc[i][j] + bias[bn + tn + j];
      if (TANH) v = tanhf(v);
      crow[j] = v;
    }
  }
}

// ---------------- one GRU step: gh = h@W_hh^T + b_hh; gates; h_out; capture last ----------------
// grid (16 j-groups of 32, 16 b-groups of 4), 256 threads.
// pair = (b_local, j_local) handled by 2 threads splitting K=512 in halves.
__global__ __launch_bounds__(256)
void gru_step(const float* __restrict__ gx_t, const float* __restrict__ h_in,
              const float* __restrict__ W_hh, const float* __restrict__ b_hh,
              const int* __restrict__ lens, int t,
              float* __restrict__ h_out, float* __restrict__ last) {
  __shared__ float hs[4][512];
  __shared__ float pr[128], pz[128], pn[128];
  const int tid = threadIdx.x;
  const int j0 = blockIdx.x << 5;   // *32
  const int b0 = blockIdx.y << 2;   // *4
  for (int i = tid; i < 512; i += 256) {      // 512 float4 = 4 rows x 128
    int bb = i >> 7, cc = i & 127;
    ((float4*)hs[bb])[cc] = ((const float4*)(h_in + (size_t)(b0 + bb) * 512))[cc];
  }
  __syncthreads();
  const int pair = tid & 127, kh = tid >> 7;
  const int bl = pair >> 5, jl = pair & 31;
  const int j = j0 + jl, b = b0 + bl;
  const float* hr = hs[bl] + (kh << 8);
  const float* wr = W_hh + (size_t)j * 512 + (kh << 8);
  const float* wz = wr + 512 * 512;
  const float* wn = wr + 1024 * 512;
  float ar = 0.f, az = 0.f, an = 0.f;
#pragma unroll 8
  for (int k = 0; k < 256; k += 4) {
    float4 h4 = *(const float4*)(hr + k);
    float4 r4 = *(const float4*)(wr + k);
    float4 z4 = *(const float4*)(wz + k);
    float4 n4 = *(const float4*)(wn + k);
    ar += h4.x * r4.x + h4.y * r4.y + h4.z * r4.z + h4.w * r4.w;
    az += h4.x * z4.x + h4.y * z4.y + h4.z * z4.z + h4.w * z4.w;
    an += h4.x * n4.x + h4.y * n4.y + h4.z * n4.z + h4.w * n4.w;
  }
  if (kh) { pr[pair] = ar; pz[pair] = az; pn[pair] = an; }
  __syncthreads();
  if (!kh) {
    ar += pr[pair]; az += pz[pair]; an += pn[pair];
    const float* gxb = gx_t + (size_t)b * 1536;
    float r = 1.f / (1.f + expf(-(gxb[j]        + ar + b_hh[j])));
    float z = 1.f / (1.f + expf(-(gxb[512 + j]  + az + b_hh[512 + j])));
    float n = tanhf(gxb[1024 + j] + r * (an + b_hh[1024 + j]));
    float hp = hs[bl][j];
    float hv = (1.f - z) * n + z * hp;
    h_out[(size_t)b * 512 + j] = hv;
    if (t == lens[b] - 1) last[(size_t)b * 512 + j] = hv;
  }
}

// ---------------- attention: energies, softmax, context (one block per b) ----------------
__global__ __launch_bounds__(256)
void attn_ctx(const float* __restrict__ histt, const float* __restrict__ last,
              float* __restrict__ ctx) {
  int b = blockIdx.x, tid = threadIdx.x;
  __shared__ float ls[512];
  __shared__ float w[256];
  __shared__ float red[256];
  ((float2*)ls)[tid] = ((const float2*)(last + (size_t)b * 512))[tid];
  __syncthreads();
  const float* hb = histt + (size_t)b * 256 * 512;
  const float* hrow = hb + (size_t)tid * 512;
  float acc = 0.f;
  for (int k = 0; k < 512; k += 4) {
    float4 h4 = *(const float4*)(hrow + k);
    acc += ls[k] * h4.x + ls[k + 1] * h4.y + ls[k + 2] * h4.z + ls[k + 3] * h4.w;
  }
  red[tid] = acc;
  __syncthreads();
  for (int s = 128; s; s >>= 1) {
    if (tid < s) red[tid] = fmaxf(red[tid], red[tid + s]);
    __syncthreads();
  }
  float m = red[0];
  __syncthreads();
  float ex = expf(acc - m);
  w[tid] = ex; red[tid] = ex;
  __syncthreads();
  for (int s = 128; s; s >>= 1) {
    if (tid < s) red[tid] += red[tid + s];
    __syncthreads();
  }
  float inv = 1.f / red[0];
  float c0 = 0.f, c1 = 0.f;
  for (int n = 0; n < 256; ++n) {
    float wn = w[n];
    c0 += wn * hb[(size_t)n * 512 + tid];
    c1 += wn * hb[(size_t)n * 512 + tid + 256];
  }
  ctx[(size_t)b * 512 + tid]       = c0 * inv;
  ctx[(size_t)b * 512 + tid + 256] = c1 * inv;
}

// ---------------- final: y[b][u] = [last|ctx|last] . W_final[u] + b_final[u] ----------------
// grid 625 blocks (8 u each), 256 threads: thread = (u_lane 0..3, b 0..63), 2 u per thread.
__global__ __launch_bounds__(256)
void final_gemm(const float* __restrict__ last, const float* __restrict__ ctx,
                const float* __restrict__ Wf, const float* __restrict__ bf,
                float* __restrict__ y) {
  __shared__ float s[64][129];
  const int tid = threadIdx.x;
  const int u0 = blockIdx.x << 3;
  const int ul = tid >> 6, b = tid & 63;
  float acc0 = 0.f, acc1 = 0.f;
  for (int kc = 0; kc < 12; ++kc) {
    __syncthreads();
    for (int i = tid; i < 2048; i += 256) {         // 64 rows x 32 float4
      int rb = i >> 5, cc = (i & 31) << 2;
      int k = kc * 128 + cc;
      const float* src = (k < 512) ? (last + (size_t)rb * 512 + k)
                       : (k < 1024) ? (ctx + (size_t)rb * 512 + k - 512)
                                    : (last + (size_t)rb * 512 + k - 1024);
      float4 v = *(const float4*)src;
      s[rb][cc] = v.x; s[rb][cc + 1] = v.y; s[rb][cc + 2] = v.z; s[rb][cc + 3] = v.w;
    }
    __syncthreads();
#pragma unroll
    for (int uu = 0; uu < 2; ++uu) {
      int u = u0 + ul + uu * 4;
      const float* wrow = Wf + (size_t)u * 1536 + kc * 128;
      float a = 0.f;
#pragma unroll 8
      for (int c = 0; c < 128; c += 4) {
        float4 w4 = *(const float4*)(wrow + c);
        a += w4.x * s[b][c] + w4.y * s[b][c + 1] + w4.z * s[b][c + 2] + w4.w * s[b][c + 3];
      }
      if (uu == 0) acc0 += a; else acc1 += a;
    }
  }
  int u = u0 + ul;
  y[(size_t)b * 5000 + u]     = acc0 + bf[u];
  y[(size_t)b * 5000 + u + 4] = acc1 + bf[u + 4];
}

// ---------------- broadcast y (B,5000) -> out (B,T,5000) ----------------
__global__ void broadcast_y(const float* __restrict__ y, float* __restrict__ out) {
  int bt = blockIdx.x;                      // b*128 + t
  const float4* src = (const float4*)(y + (size_t)(bt >> 7) * 5000);
  float4* dst = (float4*)(out + (size_t)bt * 5000);
  for (int i = threadIdx.x; i < 1250; i += 256) dst[i] = src[i];
}

extern "C" void kernel_launch(void* const* d_in, const int* in_sizes, int n_in,
                              void* d_out, int out_size, void* d_ws, size_t ws_size,
                              hipStream_t stream) {
  const int* loc  = (const int*)d_in[0];
  const int* tim  = (const int*)d_in[1];
  const int* lens = (const int*)d_in[2];
  const int* hloc = (const int*)d_in[3];
  const int* htim = (const int*)d_in[4];
  const int* huid = (const int*)d_in[5];
  // d_in[6] = group_size (constant 4, baked in)
  const float* eloc    = (const float*)d_in[7];
  const float* etim    = (const float*)d_in[8];
  const float* euid    = (const float*)d_in[9];
  const float* W_attn  = (const float*)d_in[10];
  const float* b_attn  = (const float*)d_in[11];
  const float* W_ih    = (const float*)d_in[12];
  const float* b_ih    = (const float*)d_in[13];
  const float* W_hh    = (const float*)d_in[14];
  const float* b_hh    = (const float*)d_in[15];
  const float* W_final = (const float*)d_in[16];
  const float* b_final = (const float*)d_in[17];
  float* out = (float*)d_out;
  char* ws = (char*)d_ws;

  // workspace layout (bytes)
  float* X     = (float*)(ws + 0ull);            // 8192*320*4   = 10,485,760
  float* gx    = (float*)(ws + 10485760ull);     // 8192*1536*4  = 50,331,648
  float* histf = (float*)(ws + 60817408ull);     // 16384*448*4  = 29,360,128
  float* histt = (float*)(ws + 90177536ull);     // 16384*512*4  = 33,554,432
  float* hA    = (float*)(ws + 123731968ull);    // 64*512*4
  float* hB    = (float*)(ws + 123863040ull);    // 64*512*4
  float* lastb = (float*)(ws + 123994112ull);    // 64*512*4
  float* ctx   = (float*)(ws + 124125184ull);    // 64*512*4
  float* yv    = (float*)(ws + 124256256ull);    // 64*5000*4 = 1,280,000  (end ~125.5 MB)

  gather_x<<<8192, 64, 0, stream>>>(loc, tim, eloc, etim, X);
  gemm_bt<false><<<dim3(12, 64), 256, 0, stream>>>(X, W_ih, b_ih, gx, 8192, 1536, 320);
  hist_feat<<<16384, 64, 0, stream>>>(hloc, htim, huid, eloc, etim, euid, histf);
  gemm_bt<true><<<dim3(4, 128), 256, 0, stream>>>(histf, W_attn, b_attn, histt, 16384, 512, 448);

  hipMemsetAsync(hA, 0, 64 * 512 * sizeof(float), stream);
  float* hcur = hA;
  float* hnext = hB;
  for (int t = 0; t < 128; ++t) {
    gru_step<<<dim3(16, 16), 256, 0, stream>>>(gx + (size_t)t * 64 * 1536, hcur, W_hh, b_hh,
                                               lens, t, hnext, lastb);
    float* tmp = hcur; hcur = hnext; hnext = tmp;
  }

  attn_ctx<<<64, 256, 0, stream>>>(histt, lastb, ctx);
  final_gemm<<<625, 256, 0, stream>>>(lastb, ctx, W_final, b_final, yv);
  broadcast_y<<<8192, 256, 0, stream>>>(yv, out);
}

// Round 2
// 1313.299 us; speedup vs baseline: 2.6840x; 2.6840x over previous
//
#include <hip/hip_runtime.h>
#include <hip/hip_bf16.h>

// Sizes (fixed): B=64 T=128 HID=512 LOC_EMB=256 TIM_EMB=64 UID_EMB=128
// L_HIST=1024 G=4, K_x=320, K_attn=448, N_gates=1536, UID_SIZE=5000

typedef __attribute__((ext_vector_type(8))) short bf16x8;
typedef __attribute__((ext_vector_type(4))) float f32x4;
typedef __attribute__((ext_vector_type(4))) unsigned short u16x4;

__device__ inline unsigned short f2bf(float x) {
  __hip_bfloat16 b = __float2bfloat16(x);
  return __builtin_bit_cast(unsigned short, b);
}

// ---------------- gather x = [emb_loc[loc], emb_tim[tim]] -> X[(t*64+b)][320] ----------------
__global__ void gather_x(const int* __restrict__ loc, const int* __restrict__ tim,
                         const float* __restrict__ eloc, const float* __restrict__ etim,
                         float* __restrict__ X) {
  int row = blockIdx.x;            // t*64 + b
  int t = row >> 6, b = row & 63;
  int tid = threadIdx.x;           // 64 threads
  float4* dst = (float4*)(X + (size_t)row * 320);
  int li = loc[b * 128 + t];
  dst[tid] = ((const float4*)(eloc + (size_t)li * 256))[tid];
  if (tid < 16) {
    int ti = tim[b * 128 + t];
    dst[64 + tid] = ((const float4*)(etim + (size_t)ti * 64))[tid];
  }
}

// ---------------- hist features: [loc(256) | tim(64) | uid_mean(128)] per (b, n) ----------------
__global__ void hist_feat(const int* __restrict__ hloc, const int* __restrict__ htim,
                          const int* __restrict__ huid,
                          const float* __restrict__ eloc, const float* __restrict__ etim,
                          const float* __restrict__ euid, float* __restrict__ histf) {
  int row = blockIdx.x;            // b*256 + n
  int b = row >> 8, n = row & 255;
  int tid = threadIdx.x;           // 64 threads
  int base = b * 1024 + (n << 2);
  float4* dst = (float4*)(histf + (size_t)row * 448);
  {
    int li = hloc[base];
    dst[tid] = ((const float4*)(eloc + (size_t)li * 256))[tid];
  }
  if (tid < 16) {
    int ti = htim[base];
    dst[64 + tid] = ((const float4*)(etim + (size_t)ti * 64))[tid];
  }
  if (tid < 32) {
    const float4* u0 = (const float4*)(euid + (size_t)huid[base + 0] * 128);
    const float4* u1 = (const float4*)(euid + (size_t)huid[base + 1] * 128);
    const float4* u2 = (const float4*)(euid + (size_t)huid[base + 2] * 128);
    const float4* u3 = (const float4*)(euid + (size_t)huid[base + 3] * 128);
    float4 v0 = u0[tid], v1 = u1[tid], v2 = u2[tid], v3 = u3[tid];
    float4 o;
    o.x = 0.25f * (v0.x + v1.x + v2.x + v3.x);
    o.y = 0.25f * (v0.y + v1.y + v2.y + v3.y);
    o.z = 0.25f * (v0.z + v1.z + v2.z + v3.z);
    o.w = 0.25f * (v0.w + v1.w + v2.w + v3.w);
    dst[80 + tid] = o;
  }
}

// ---------------- fp32 tiled GEMM: C[m][n] = act(sum_k A[m][k]*B[n][k] + bias[n]) ----------------
template<bool TANH>
__global__ __launch_bounds__(256)
void gemm_bt(const float* __restrict__ A, const float* __restrict__ Bm,
             const float* __restrict__ bias, float* __restrict__ C,
             int M, int N, int K) {
  constexpr int BM = 128, BN = 128, BK = 16;
  __shared__ float As[BK][BM + 4];
  __shared__ float Bs[BK][BN + 4];
  const int tid = threadIdx.x;
  const int bm = blockIdx.y * BM, bn = blockIdx.x * BN;
  const int tm = (tid >> 4) << 3, tn = (tid & 15) << 3;
  const int lr = tid >> 2;
  const int lc = (tid & 3) << 2;
  const float* Ap0 = A + (size_t)(bm + lr) * K + lc;
  const float* Ap1 = A + (size_t)(bm + 64 + lr) * K + lc;
  const float* Bp0 = Bm + (size_t)(bn + lr) * K + lc;
  const float* Bp1 = Bm + (size_t)(bn + 64 + lr) * K + lc;
  float acc[8][8] = {};
  for (int k0 = 0; k0 < K; k0 += BK) {
    float4 a0 = *(const float4*)(Ap0 + k0);
    float4 a1 = *(const float4*)(Ap1 + k0);
    float4 b0 = *(const float4*)(Bp0 + k0);
    float4 b1 = *(const float4*)(Bp1 + k0);
    As[lc + 0][lr] = a0.x; As[lc + 1][lr] = a0.y; As[lc + 2][lr] = a0.z; As[lc + 3][lr] = a0.w;
    As[lc + 0][64 + lr] = a1.x; As[lc + 1][64 + lr] = a1.y; As[lc + 2][64 + lr] = a1.z; As[lc + 3][64 + lr] = a1.w;
    Bs[lc + 0][lr] = b0.x; Bs[lc + 1][lr] = b0.y; Bs[lc + 2][lr] = b0.z; Bs[lc + 3][lr] = b0.w;
    Bs[lc + 0][64 + lr] = b1.x; Bs[lc + 1][64 + lr] = b1.y; Bs[lc + 2][64 + lr] = b1.z; Bs[lc + 3][64 + lr] = b1.w;
    __syncthreads();
#pragma unroll
    for (int kk = 0; kk < BK; ++kk) {
      float a[8], bv[8];
      *(float4*)&a[0]  = *(const float4*)&As[kk][tm];
      *(float4*)&a[4]  = *(const float4*)&As[kk][tm + 4];
      *(float4*)&bv[0] = *(const float4*)&Bs[kk][tn];
      *(float4*)&bv[4] = *(const float4*)&Bs[kk][tn + 4];
#pragma unroll
      for (int i = 0; i < 8; ++i)
#pragma unroll
        for (int j = 0; j < 8; ++j)
          acc[i][j] += a[i] * bv[j];
    }
    __syncthreads();
  }
#pragma unroll
  for (int i = 0; i < 8; ++i) {
    float* crow = C + (size_t)(bm + tm + i) * N + bn + tn;
#pragma unroll
    for (int j = 0; j < 8; ++j) {
      float v = acc[i][j] + bias[bn + tn + j];
      if (TANH) v = tanhf(v);
      crow[j] = v;
    }
  }
}

// ---------------- persistent GRU: all 128 steps in one kernel ----------------
// 128 blocks x 64 threads. block = (chunk c = bid>>2 in [0,32), group g = bid&3 in [0,4)).
// Block owns h-outputs j in [16c,16c+16) and batches b in [16g,16g+16).
// W_hh slice (3 gates x 16 rows x 512) held in LDS as bf16, XOR-swizzled.
// h exchanged via double-buffered global bf16 [2][64][512]; h fp32 kept in regs.
// Per-group 32-block barrier: agent-scope release/acquire counter in ws.
__global__ __launch_bounds__(64)
void gru_persist(const float* __restrict__ gx, const float* __restrict__ W_hh,
                 const float* __restrict__ b_hh, const int* __restrict__ lens,
                 short* __restrict__ h_bf, float* __restrict__ lastb,
                 unsigned int* __restrict__ cnt) {
  __shared__ short wlds[3 * 16 * 512];   // 48 KB
  const int lane = threadIdx.x;
  const int bid = blockIdx.x;
  const int c = bid >> 2, grp = bid & 3;
  const int j0 = c << 4;                 // h-output base
  const int b0 = grp << 4;               // batch base
  const int m16 = lane & 15, g4 = lane >> 4;

  // ---- load weight slice into LDS (once), fp32 -> bf16, swizzled ----
  for (int g = 0; g < 3; ++g) {
    const float* wg = W_hh + (size_t)(g * 512 + j0) * 512;
    for (int i = 0; i < 16; ++i) {
      int row = i;                        // one row per iteration, 64 lanes cover 512 cols
      int k = lane << 3;
      const float4* src = (const float4*)(wg + (size_t)row * 512 + k);
      float4 f0 = src[0], f1 = src[1];
      bf16x8 w;
      w[0] = (short)f2bf(f0.x); w[1] = (short)f2bf(f0.y);
      w[2] = (short)f2bf(f0.z); w[3] = (short)f2bf(f0.w);
      w[4] = (short)f2bf(f1.x); w[5] = (short)f2bf(f1.y);
      w[6] = (short)f2bf(f1.z); w[7] = (short)f2bf(f1.w);
      int off = ((row << 9) + k) ^ ((row & 7) << 3);   // short units
      *(bf16x8*)(wlds + (g << 13) + off) = w;
    }
  }

  // ---- per-lane constants ----
  const int jrow = j0 + (g4 << 2);       // 4 consecutive j rows for this lane
  const int bcol = b0 + m16;             // this lane's batch
  const f32x4 bhr = *(const f32x4*)&b_hh[jrow];
  const f32x4 bhz = *(const f32x4*)&b_hh[512 + jrow];
  const f32x4 bhn = *(const f32x4*)&b_hh[1024 + jrow];
  const int lenb = lens[bcol];
  f32x4 hprev = {0.f, 0.f, 0.f, 0.f};

  for (int t = 0; t < 128; ++t) {
    const float* gxb = gx + ((size_t)t * 64 + bcol) * 1536 + jrow;
    f32x4 gr = *(const f32x4*)gxb;
    f32x4 gz = *(const f32x4*)(gxb + 512);
    f32x4 gn = *(const f32x4*)(gxb + 1024);
    f32x4 ar = {0.f, 0.f, 0.f, 0.f}, az = ar, an = ar;
    if (t) {
      const short* hrow = h_bf + ((t & 1) << 15) + (size_t)(b0 + m16) * 512 + (g4 << 3);
#pragma unroll
      for (int ks = 0; ks < 16; ++ks) {
        int k = (ks << 5) + (g4 << 3);
        int off = ((m16 << 9) + k) ^ ((m16 & 7) << 3);
        bf16x8 bfrag = *(const bf16x8*)(hrow + (ks << 5));
        ar = __builtin_amdgcn_mfma_f32_16x16x32_bf16(*(const bf16x8*)(wlds + off), bfrag, ar, 0, 0, 0);
        az = __builtin_amdgcn_mfma_f32_16x16x32_bf16(*(const bf16x8*)(wlds + 8192 + off), bfrag, az, 0, 0, 0);
        an = __builtin_amdgcn_mfma_f32_16x16x32_bf16(*(const bf16x8*)(wlds + 16384 + off), bfrag, an, 0, 0, 0);
      }
    }
    u16x4 hw;
#pragma unroll
    for (int q = 0; q < 4; ++q) {
      float r = 1.f / (1.f + expf(-(gr[q] + ar[q] + bhr[q])));
      float z = 1.f / (1.f + expf(-(gz[q] + az[q] + bhz[q])));
      float n = tanhf(gn[q] + r * (an[q] + bhn[q]));
      float hv = (1.f - z) * n + z * hprev[q];
      hprev[q] = hv;
      hw[q] = f2bf(hv);
    }
    short* hbw = h_bf + ((~t & 1) << 15);
    *(u16x4*)(hbw + (size_t)bcol * 512 + jrow) = hw;
    if (t == lenb - 1) {
      *(f32x4*)(lastb + (size_t)bcol * 512 + jrow) = hprev;
    }
    if (t < 127) {
      if (lane == 0)
        __hip_atomic_fetch_add(cnt + grp, 1u, __ATOMIC_RELEASE, __HIP_MEMORY_SCOPE_AGENT);
      unsigned tgt = 32u * (unsigned)(t + 1);
      while (__hip_atomic_load(cnt + grp, __ATOMIC_ACQUIRE, __HIP_MEMORY_SCOPE_AGENT) < tgt)
        __builtin_amdgcn_s_sleep(1);
    }
  }
}

// ---------------- attention: energies, softmax, context (one block per b) ----------------
__global__ __launch_bounds__(256)
void attn_ctx(const float* __restrict__ histt, const float* __restrict__ last,
              float* __restrict__ ctx) {
  int b = blockIdx.x, tid = threadIdx.x;
  __shared__ float ls[512];
  __shared__ float w[256];
  __shared__ float red[256];
  ((float2*)ls)[tid] = ((const float2*)(last + (size_t)b * 512))[tid];
  __syncthreads();
  const float* hb = histt + (size_t)b * 256 * 512;
  const float* hrow = hb + (size_t)tid * 512;
  float acc = 0.f;
  for (int k = 0; k < 512; k += 4) {
    float4 h4 = *(const float4*)(hrow + k);
    acc += ls[k] * h4.x + ls[k + 1] * h4.y + ls[k + 2] * h4.z + ls[k + 3] * h4.w;
  }
  red[tid] = acc;
  __syncthreads();
  for (int s = 128; s; s >>= 1) {
    if (tid < s) red[tid] = fmaxf(red[tid], red[tid + s]);
    __syncthreads();
  }
  float m = red[0];
  __syncthreads();
  float ex = expf(acc - m);
  w[tid] = ex; red[tid] = ex;
  __syncthreads();
  for (int s = 128; s; s >>= 1) {
    if (tid < s) red[tid] += red[tid + s];
    __syncthreads();
  }
  float inv = 1.f / red[0];
  float c0 = 0.f, c1 = 0.f;
  for (int n = 0; n < 256; ++n) {
    float wn = w[n];
    c0 += wn * hb[(size_t)n * 512 + tid];
    c1 += wn * hb[(size_t)n * 512 + tid + 256];
  }
  ctx[(size_t)b * 512 + tid]       = c0 * inv;
  ctx[(size_t)b * 512 + tid + 256] = c1 * inv;
}

// ---------------- final: y[b][u] = [last|ctx|last] . W_final[u] + b_final[u] ----------------
__global__ __launch_bounds__(256)
void final_gemm(const float* __restrict__ last, const float* __restrict__ ctx,
                const float* __restrict__ Wf, const float* __restrict__ bf,
                float* __restrict__ y) {
  __shared__ float s[64][129];
  const int tid = threadIdx.x;
  const int u0 = blockIdx.x << 3;
  const int ul = tid >> 6, b = tid & 63;
  float acc0 = 0.f, acc1 = 0.f;
  for (int kc = 0; kc < 12; ++kc) {
    __syncthreads();
    for (int i = tid; i < 2048; i += 256) {
      int rb = i >> 5, cc = (i & 31) << 2;
      int k = kc * 128 + cc;
      const float* src = (k < 512) ? (last + (size_t)rb * 512 + k)
                       : (k < 1024) ? (ctx + (size_t)rb * 512 + k - 512)
                                    : (last + (size_t)rb * 512 + k - 1024);
      float4 v = *(const float4*)src;
      s[rb][cc] = v.x; s[rb][cc + 1] = v.y; s[rb][cc + 2] = v.z; s[rb][cc + 3] = v.w;
    }
    __syncthreads();
#pragma unroll
    for (int uu = 0; uu < 2; ++uu) {
      int u = u0 + ul + uu * 4;
      const float* wrow = Wf + (size_t)u * 1536 + kc * 128;
      float a = 0.f;
#pragma unroll 8
      for (int c = 0; c < 128; c += 4) {
        float4 w4 = *(const float4*)(wrow + c);
        a += w4.x * s[b][c] + w4.y * s[b][c + 1] + w4.z * s[b][c + 2] + w4.w * s[b][c + 3];
      }
      if (uu == 0) acc0 += a; else acc1 += a;
    }
  }
  int u = u0 + ul;
  y[(size_t)b * 5000 + u]     = acc0 + bf[u];
  y[(size_t)b * 5000 + u + 4] = acc1 + bf[u + 4];
}

// ---------------- broadcast y (B,5000) -> out (B,T,5000) ----------------
__global__ void broadcast_y(const float* __restrict__ y, float* __restrict__ out) {
  int bt = blockIdx.x;
  const float4* src = (const float4*)(y + (size_t)(bt >> 7) * 5000);
  float4* dst = (float4*)(out + (size_t)bt * 5000);
  for (int i = threadIdx.x; i < 1250; i += 256) dst[i] = src[i];
}

extern "C" void kernel_launch(void* const* d_in, const int* in_sizes, int n_in,
                              void* d_out, int out_size, void* d_ws, size_t ws_size,
                              hipStream_t stream) {
  const int* loc  = (const int*)d_in[0];
  const int* tim  = (const int*)d_in[1];
  const int* lens = (const int*)d_in[2];
  const int* hloc = (const int*)d_in[3];
  const int* htim = (const int*)d_in[4];
  const int* huid = (const int*)d_in[5];
  // d_in[6] = group_size (constant 4, baked in)
  const float* eloc    = (const float*)d_in[7];
  const float* etim    = (const float*)d_in[8];
  const float* euid    = (const float*)d_in[9];
  const float* W_attn  = (const float*)d_in[10];
  const float* b_attn  = (const float*)d_in[11];
  const float* W_ih    = (const float*)d_in[12];
  const float* b_ih    = (const float*)d_in[13];
  const float* W_hh    = (const float*)d_in[14];
  const float* b_hh    = (const float*)d_in[15];
  const float* W_final = (const float*)d_in[16];
  const float* b_final = (const float*)d_in[17];
  float* out = (float*)d_out;
  char* ws = (char*)d_ws;

  // workspace layout (bytes)
  float* X     = (float*)(ws + 0ull);            // 8192*320*4   = 10,485,760
  float* gx    = (float*)(ws + 10485760ull);     // 8192*1536*4  = 50,331,648
  float* histf = (float*)(ws + 60817408ull);     // 16384*448*4  = 29,360,128
  float* histt = (float*)(ws + 90177536ull);     // 16384*512*4  = 33,554,432
  float* lastb = (float*)(ws + 123731968ull);    // 64*512*4
  float* ctx   = (float*)(ws + 123863040ull);    // 64*512*4
  float* yv    = (float*)(ws + 123994112ull);    // 64*5000*4 = 1,280,000
  short* h_bf  = (short*)(ws + 125274112ull);    // 2*64*512*2 = 131,072
  unsigned int* cnt = (unsigned int*)(ws + 125405184ull);  // 4 counters

  gather_x<<<8192, 64, 0, stream>>>(loc, tim, eloc, etim, X);
  gemm_bt<false><<<dim3(12, 64), 256, 0, stream>>>(X, W_ih, b_ih, gx, 8192, 1536, 320);
  hist_feat<<<16384, 64, 0, stream>>>(hloc, htim, huid, eloc, etim, euid, histf);
  gemm_bt<true><<<dim3(4, 128), 256, 0, stream>>>(histf, W_attn, b_attn, histt, 16384, 512, 448);

  hipMemsetAsync(cnt, 0, 16, stream);
  gru_persist<<<128, 64, 0, stream>>>(gx, W_hh, b_hh, lens, h_bf, lastb, cnt);

  attn_ctx<<<64, 256, 0, stream>>>(histt, lastb, ctx);
  final_gemm<<<625, 256, 0, stream>>>(lastb, ctx, W_final, b_final, yv);
  broadcast_y<<<8192, 256, 0, stream>>>(yv, out);
}

// Round 3
// 1092.421 us; speedup vs baseline: 3.2267x; 1.2022x over previous
//
#include <hip/hip_runtime.h>
#include <hip/hip_bf16.h>

// Sizes (fixed): B=64 T=128 HID=512 LOC_EMB=256 TIM_EMB=64 UID_EMB=128
// L_HIST=1024 G=4, K_x=320, K_attn=448, N_gates=1536, UID_SIZE=5000

typedef __attribute__((ext_vector_type(8))) short bf16x8;
typedef __attribute__((ext_vector_type(4))) float f32x4;
typedef __attribute__((ext_vector_type(4))) unsigned short u16x4;

__device__ inline unsigned short f2bf(float x) {
  __hip_bfloat16 b = __float2bfloat16(x);
  return __builtin_bit_cast(unsigned short, b);
}

// ---------------- gather x = [emb_loc[loc], emb_tim[tim]] -> X[(t*64+b)][320] ----------------
__global__ void gather_x(const int* __restrict__ loc, const int* __restrict__ tim,
                         const float* __restrict__ eloc, const float* __restrict__ etim,
                         float* __restrict__ X) {
  int row = blockIdx.x;            // t*64 + b
  int t = row >> 6, b = row & 63;
  int tid = threadIdx.x;           // 64 threads
  float4* dst = (float4*)(X + (size_t)row * 320);
  int li = loc[b * 128 + t];
  dst[tid] = ((const float4*)(eloc + (size_t)li * 256))[tid];
  if (tid < 16) {
    int ti = tim[b * 128 + t];
    dst[64 + tid] = ((const float4*)(etim + (size_t)ti * 64))[tid];
  }
}

// ---------------- hist features: [loc(256) | tim(64) | uid_mean(128)] per (b, n) ----------------
__global__ void hist_feat(const int* __restrict__ hloc, const int* __restrict__ htim,
                          const int* __restrict__ huid,
                          const float* __restrict__ eloc, const float* __restrict__ etim,
                          const float* __restrict__ euid, float* __restrict__ histf) {
  int row = blockIdx.x;            // b*256 + n
  int b = row >> 8, n = row & 255;
  int tid = threadIdx.x;           // 64 threads
  int base = b * 1024 + (n << 2);
  float4* dst = (float4*)(histf + (size_t)row * 448);
  {
    int li = hloc[base];
    dst[tid] = ((const float4*)(eloc + (size_t)li * 256))[tid];
  }
  if (tid < 16) {
    int ti = htim[base];
    dst[64 + tid] = ((const float4*)(etim + (size_t)ti * 64))[tid];
  }
  if (tid < 32) {
    const float4* u0 = (const float4*)(euid + (size_t)huid[base + 0] * 128);
    const float4* u1 = (const float4*)(euid + (size_t)huid[base + 1] * 128);
    const float4* u2 = (const float4*)(euid + (size_t)huid[base + 2] * 128);
    const float4* u3 = (const float4*)(euid + (size_t)huid[base + 3] * 128);
    float4 v0 = u0[tid], v1 = u1[tid], v2 = u2[tid], v3 = u3[tid];
    float4 o;
    o.x = 0.25f * (v0.x + v1.x + v2.x + v3.x);
    o.y = 0.25f * (v0.y + v1.y + v2.y + v3.y);
    o.z = 0.25f * (v0.z + v1.z + v2.z + v3.z);
    o.w = 0.25f * (v0.w + v1.w + v2.w + v3.w);
    dst[80 + tid] = o;
  }
}

// ---------------- fp32 tiled GEMM: C[m][n] = act(sum_k A[m][k]*B[n][k] + bias[n]) ----------------
template<bool TANH>
__global__ __launch_bounds__(256)
void gemm_bt(const float* __restrict__ A, const float* __restrict__ Bm,
             const float* __restrict__ bias, float* __restrict__ C,
             int M, int N, int K) {
  constexpr int BM = 128, BN = 128, BK = 16;
  __shared__ float As[BK][BM + 4];
  __shared__ float Bs[BK][BN + 4];
  const int tid = threadIdx.x;
  const int bm = blockIdx.y * BM, bn = blockIdx.x * BN;
  const int tm = (tid >> 4) << 3, tn = (tid & 15) << 3;
  const int lr = tid >> 2;
  const int lc = (tid & 3) << 2;
  const float* Ap0 = A + (size_t)(bm + lr) * K + lc;
  const float* Ap1 = A + (size_t)(bm + 64 + lr) * K + lc;
  const float* Bp0 = Bm + (size_t)(bn + lr) * K + lc;
  const float* Bp1 = Bm + (size_t)(bn + 64 + lr) * K + lc;
  float acc[8][8] = {};
  for (int k0 = 0; k0 < K; k0 += BK) {
    float4 a0 = *(const float4*)(Ap0 + k0);
    float4 a1 = *(const float4*)(Ap1 + k0);
    float4 b0 = *(const float4*)(Bp0 + k0);
    float4 b1 = *(const float4*)(Bp1 + k0);
    As[lc + 0][lr] = a0.x; As[lc + 1][lr] = a0.y; As[lc + 2][lr] = a0.z; As[lc + 3][lr] = a0.w;
    As[lc + 0][64 + lr] = a1.x; As[lc + 1][64 + lr] = a1.y; As[lc + 2][64 + lr] = a1.z; As[lc + 3][64 + lr] = a1.w;
    Bs[lc + 0][lr] = b0.x; Bs[lc + 1][lr] = b0.y; Bs[lc + 2][lr] = b0.z; Bs[lc + 3][lr] = b0.w;
    Bs[lc + 0][64 + lr] = b1.x; Bs[lc + 1][64 + lr] = b1.y; Bs[lc + 2][64 + lr] = b1.z; Bs[lc + 3][64 + lr] = b1.w;
    __syncthreads();
#pragma unroll
    for (int kk = 0; kk < BK; ++kk) {
      float a[8], bv[8];
      *(float4*)&a[0]  = *(const float4*)&As[kk][tm];
      *(float4*)&a[4]  = *(const float4*)&As[kk][tm + 4];
      *(float4*)&bv[0] = *(const float4*)&Bs[kk][tn];
      *(float4*)&bv[4] = *(const float4*)&Bs[kk][tn + 4];
#pragma unroll
      for (int i = 0; i < 8; ++i)
#pragma unroll
        for (int j = 0; j < 8; ++j)
          acc[i][j] += a[i] * bv[j];
    }
    __syncthreads();
  }
#pragma unroll
  for (int i = 0; i < 8; ++i) {
    float* crow = C + (size_t)(bm + tm + i) * N + bn + tn;
#pragma unroll
    for (int j = 0; j < 8; ++j) {
      float v = acc[i][j] + bias[bn + tn + j];
      if (TANH) v = tanhf(v);
      crow[j] = v;
    }
  }
}

// ---------------- persistent GRU: all 128 steps in one kernel ----------------
// 64 blocks x 64 threads (1 wave). block = (chunk c = bid>>2 in [0,16), group g = bid&3).
// Block owns j in [32c, 32c+32) and batches [16g, 16g+16).
// W_hh slice (3 gates x 32 rows x 512) in LDS as bf16 (96 KB), XOR-swizzled.
// h exchanged via double-buffered global bf16 [2][64][512].
// Barrier: per-block release flag (own 64B line) + relaxed polling + one acquire fence.
__global__ __launch_bounds__(64)
void gru_persist(const float* __restrict__ gx, const float* __restrict__ W_hh,
                 const float* __restrict__ b_hh, const int* __restrict__ lens,
                 short* __restrict__ h_bf, float* __restrict__ lastb,
                 unsigned int* __restrict__ flags) {
  __shared__ short wlds[6 * 16 * 512];   // 6 slabs (3 gates x 2 j-subtiles) x 16x512 bf16 = 96 KB
  const int lane = threadIdx.x;
  const int bid = blockIdx.x;
  const int c = bid >> 2, grp = bid & 3;
  const int j0 = c << 5;                 // 32 j rows
  const int b0 = grp << 4;               // 16 batches
  const int m16 = lane & 15, g4 = lane >> 4;

  // ---- load weight slice into LDS (once), fp32 -> bf16, swizzled ----
  for (int s = 0; s < 6; ++s) {          // s = g*2 + tt
    int g = s >> 1, tt = s & 1;
    const float* wg = W_hh + (size_t)(g * 512 + j0 + tt * 16) * 512;
    for (int r = 0; r < 16; ++r) {
      int k = lane << 3;
      const float4* src = (const float4*)(wg + (size_t)r * 512 + k);
      float4 f0 = src[0], f1 = src[1];
      bf16x8 w;
      w[0] = (short)f2bf(f0.x); w[1] = (short)f2bf(f0.y);
      w[2] = (short)f2bf(f0.z); w[3] = (short)f2bf(f0.w);
      w[4] = (short)f2bf(f1.x); w[5] = (short)f2bf(f1.y);
      w[6] = (short)f2bf(f1.z); w[7] = (short)f2bf(f1.w);
      int off = ((r << 9) + k) ^ ((r & 7) << 3);   // short units
      *(bf16x8*)(wlds + (s << 13) + off) = w;
    }
  }

  // ---- per-lane constants ----
  const int bcol = b0 + m16;             // this lane's batch
  const int jr0 = j0 + (g4 << 2);        // j rows for tt=0
  const int jr1 = jr0 + 16;              // j rows for tt=1
  const f32x4 bhr0 = *(const f32x4*)&b_hh[jr0];
  const f32x4 bhz0 = *(const f32x4*)&b_hh[512 + jr0];
  const f32x4 bhn0 = *(const f32x4*)&b_hh[1024 + jr0];
  const f32x4 bhr1 = *(const f32x4*)&b_hh[jr1];
  const f32x4 bhz1 = *(const f32x4*)&b_hh[512 + jr1];
  const f32x4 bhn1 = *(const f32x4*)&b_hh[1024 + jr1];
  const int lenb = lens[bcol];
  f32x4 hprev0 = {0.f, 0.f, 0.f, 0.f}, hprev1 = {0.f, 0.f, 0.f, 0.f};

  unsigned int* gflags = flags + (grp << 8);       // 16 flags x 16 dwords (64B) apart
  unsigned int* ownflag = gflags + (c << 4);

  for (int t = 0; t < 128; ++t) {
    // gx loads first: independent of h, latency hides under the flag wait
    const float* gxb = gx + ((size_t)t * 64 + bcol) * 1536;
    f32x4 gr0 = *(const f32x4*)(gxb + jr0);
    f32x4 gz0 = *(const f32x4*)(gxb + 512 + jr0);
    f32x4 gn0 = *(const f32x4*)(gxb + 1024 + jr0);
    f32x4 gr1 = *(const f32x4*)(gxb + jr1);
    f32x4 gz1 = *(const f32x4*)(gxb + 512 + jr1);
    f32x4 gn1 = *(const f32x4*)(gxb + 1024 + jr1);

    f32x4 ar0 = {0.f, 0.f, 0.f, 0.f}, az0 = ar0, an0 = ar0;
    f32x4 ar1 = ar0, az1 = ar0, an1 = ar0;
    if (t) {
      // wait: all 16 chunk-blocks of this group finished step t-1
      unsigned tgt = (unsigned)t;
      while (true) {
        unsigned f = tgt;
        if (lane < 16)
          f = __hip_atomic_load(gflags + (lane << 4), __ATOMIC_RELAXED, __HIP_MEMORY_SCOPE_AGENT);
        if (__all((int)(f >= tgt))) break;
        __builtin_amdgcn_s_sleep(1);
      }
      __builtin_amdgcn_fence(__ATOMIC_ACQUIRE, "agent");

      const short* hrow = h_bf + ((t & 1) << 15) + (size_t)bcol * 512 + (g4 << 3);
      bf16x8 hf0  = *(const bf16x8*)(hrow);
      bf16x8 hf1  = *(const bf16x8*)(hrow + 32);
      bf16x8 hf2  = *(const bf16x8*)(hrow + 64);
      bf16x8 hf3  = *(const bf16x8*)(hrow + 96);
      bf16x8 hf4  = *(const bf16x8*)(hrow + 128);
      bf16x8 hf5  = *(const bf16x8*)(hrow + 160);
      bf16x8 hf6  = *(const bf16x8*)(hrow + 192);
      bf16x8 hf7  = *(const bf16x8*)(hrow + 224);
      bf16x8 hf8  = *(const bf16x8*)(hrow + 256);
      bf16x8 hf9  = *(const bf16x8*)(hrow + 288);
      bf16x8 hf10 = *(const bf16x8*)(hrow + 320);
      bf16x8 hf11 = *(const bf16x8*)(hrow + 352);
      bf16x8 hf12 = *(const bf16x8*)(hrow + 384);
      bf16x8 hf13 = *(const bf16x8*)(hrow + 416);
      bf16x8 hf14 = *(const bf16x8*)(hrow + 448);
      bf16x8 hf15 = *(const bf16x8*)(hrow + 480);
#define GRU_MFMA(ks, hf)                                                            \
      {                                                                             \
        int off = ((m16 << 9) + (ks << 5) + (g4 << 3)) ^ ((m16 & 7) << 3);          \
        ar0 = __builtin_amdgcn_mfma_f32_16x16x32_bf16(*(const bf16x8*)(wlds + off), hf, ar0, 0, 0, 0);              \
        ar1 = __builtin_amdgcn_mfma_f32_16x16x32_bf16(*(const bf16x8*)(wlds + 8192 + off), hf, ar1, 0, 0, 0);       \
        az0 = __builtin_amdgcn_mfma_f32_16x16x32_bf16(*(const bf16x8*)(wlds + 16384 + off), hf, az0, 0, 0, 0);      \
        az1 = __builtin_amdgcn_mfma_f32_16x16x32_bf16(*(const bf16x8*)(wlds + 24576 + off), hf, az1, 0, 0, 0);      \
        an0 = __builtin_amdgcn_mfma_f32_16x16x32_bf16(*(const bf16x8*)(wlds + 32768 + off), hf, an0, 0, 0, 0);      \
        an1 = __builtin_amdgcn_mfma_f32_16x16x32_bf16(*(const bf16x8*)(wlds + 40960 + off), hf, an1, 0, 0, 0);      \
      }
      GRU_MFMA(0, hf0)   GRU_MFMA(1, hf1)   GRU_MFMA(2, hf2)   GRU_MFMA(3, hf3)
      GRU_MFMA(4, hf4)   GRU_MFMA(5, hf5)   GRU_MFMA(6, hf6)   GRU_MFMA(7, hf7)
      GRU_MFMA(8, hf8)   GRU_MFMA(9, hf9)   GRU_MFMA(10, hf10) GRU_MFMA(11, hf11)
      GRU_MFMA(12, hf12) GRU_MFMA(13, hf13) GRU_MFMA(14, hf14) GRU_MFMA(15, hf15)
#undef GRU_MFMA
    }
    u16x4 hw0, hw1;
#pragma unroll
    for (int q = 0; q < 4; ++q) {
      float r = 1.f / (1.f + expf(-(gr0[q] + ar0[q] + bhr0[q])));
      float z = 1.f / (1.f + expf(-(gz0[q] + az0[q] + bhz0[q])));
      float n = tanhf(gn0[q] + r * (an0[q] + bhn0[q]));
      float hv = (1.f - z) * n + z * hprev0[q];
      hprev0[q] = hv;
      hw0[q] = f2bf(hv);
    }
#pragma unroll
    for (int q = 0; q < 4; ++q) {
      float r = 1.f / (1.f + expf(-(gr1[q] + ar1[q] + bhr1[q])));
      float z = 1.f / (1.f + expf(-(gz1[q] + az1[q] + bhz1[q])));
      float n = tanhf(gn1[q] + r * (an1[q] + bhn1[q]));
      float hv = (1.f - z) * n + z * hprev1[q];
      hprev1[q] = hv;
      hw1[q] = f2bf(hv);
    }
    short* hbw = h_bf + ((~t & 1) << 15) + (size_t)bcol * 512;
    *(u16x4*)(hbw + jr0) = hw0;
    *(u16x4*)(hbw + jr1) = hw1;
    if (t == lenb - 1) {
      *(f32x4*)(lastb + (size_t)bcol * 512 + jr0) = hprev0;
      *(f32x4*)(lastb + (size_t)bcol * 512 + jr1) = hprev1;
    }
    if (t < 127) {
      __builtin_amdgcn_fence(__ATOMIC_RELEASE, "agent");
      if (lane == 0)
        __hip_atomic_store(ownflag, (unsigned)(t + 1), __ATOMIC_RELAXED, __HIP_MEMORY_SCOPE_AGENT);
    }
  }
}

// ---------------- attention: energies, softmax, context (one block per b) ----------------
__global__ __launch_bounds__(256)
void attn_ctx(const float* __restrict__ histt, const float* __restrict__ last,
              float* __restrict__ ctx) {
  int b = blockIdx.x, tid = threadIdx.x;
  __shared__ float ls[512];
  __shared__ float w[256];
  __shared__ float red[256];
  ((float2*)ls)[tid] = ((const float2*)(last + (size_t)b * 512))[tid];
  __syncthreads();
  const float* hb = histt + (size_t)b * 256 * 512;
  const float* hrow = hb + (size_t)tid * 512;
  float acc = 0.f;
  for (int k = 0; k < 512; k += 4) {
    float4 h4 = *(const float4*)(hrow + k);
    acc += ls[k] * h4.x + ls[k + 1] * h4.y + ls[k + 2] * h4.z + ls[k + 3] * h4.w;
  }
  red[tid] = acc;
  __syncthreads();
  for (int s = 128; s; s >>= 1) {
    if (tid < s) red[tid] = fmaxf(red[tid], red[tid + s]);
    __syncthreads();
  }
  float m = red[0];
  __syncthreads();
  float ex = expf(acc - m);
  w[tid] = ex; red[tid] = ex;
  __syncthreads();
  for (int s = 128; s; s >>= 1) {
    if (tid < s) red[tid] += red[tid + s];
    __syncthreads();
  }
  float inv = 1.f / red[0];
  float c0 = 0.f, c1 = 0.f;
  for (int n = 0; n < 256; ++n) {
    float wn = w[n];
    c0 += wn * hb[(size_t)n * 512 + tid];
    c1 += wn * hb[(size_t)n * 512 + tid + 256];
  }
  ctx[(size_t)b * 512 + tid]       = c0 * inv;
  ctx[(size_t)b * 512 + tid + 256] = c1 * inv;
}

// ---------------- final: y[b][u] = [last|ctx|last] . W_final[u] + b_final[u] ----------------
__global__ __launch_bounds__(256)
void final_gemm(const float* __restrict__ last, const float* __restrict__ ctx,
                const float* __restrict__ Wf, const float* __restrict__ bf,
                float* __restrict__ y) {
  __shared__ float s[64][129];
  const int tid = threadIdx.x;
  const int u0 = blockIdx.x << 3;
  const int ul = tid >> 6, b = tid & 63;
  float acc0 = 0.f, acc1 = 0.f;
  for (int kc = 0; kc < 12; ++kc) {
    __syncthreads();
    for (int i = tid; i < 2048; i += 256) {
      int rb = i >> 5, cc = (i & 31) << 2;
      int k = kc * 128 + cc;
      const float* src = (k < 512) ? (last + (size_t)rb * 512 + k)
                       : (k < 1024) ? (ctx + (size_t)rb * 512 + k - 512)
                                    : (last + (size_t)rb * 512 + k - 1024);
      float4 v = *(const float4*)src;
      s[rb][cc] = v.x; s[rb][cc + 1] = v.y; s[rb][cc + 2] = v.z; s[rb][cc + 3] = v.w;
    }
    __syncthreads();
#pragma unroll
    for (int uu = 0; uu < 2; ++uu) {
      int u = u0 + ul + uu * 4;
      const float* wrow = Wf + (size_t)u * 1536 + kc * 128;
      float a = 0.f;
#pragma unroll 8
      for (int c = 0; c < 128; c += 4) {
        float4 w4 = *(const float4*)(wrow + c);
        a += w4.x * s[b][c] + w4.y * s[b][c + 1] + w4.z * s[b][c + 2] + w4.w * s[b][c + 3];
      }
      if (uu == 0) acc0 += a; else acc1 += a;
    }
  }
  int u = u0 + ul;
  y[(size_t)b * 5000 + u]     = acc0 + bf[u];
  y[(size_t)b * 5000 + u + 4] = acc1 + bf[u + 4];
}

// ---------------- broadcast y (B,5000) -> out (B,T,5000) ----------------
__global__ void broadcast_y(const float* __restrict__ y, float* __restrict__ out) {
  int bt = blockIdx.x;
  const float4* src = (const float4*)(y + (size_t)(bt >> 7) * 5000);
  float4* dst = (float4*)(out + (size_t)bt * 5000);
  for (int i = threadIdx.x; i < 1250; i += 256) dst[i] = src[i];
}

extern "C" void kernel_launch(void* const* d_in, const int* in_sizes, int n_in,
                              void* d_out, int out_size, void* d_ws, size_t ws_size,
                              hipStream_t stream) {
  const int* loc  = (const int*)d_in[0];
  const int* tim  = (const int*)d_in[1];
  const int* lens = (const int*)d_in[2];
  const int* hloc = (const int*)d_in[3];
  const int* htim = (const int*)d_in[4];
  const int* huid = (const int*)d_in[5];
  // d_in[6] = group_size (constant 4, baked in)
  const float* eloc    = (const float*)d_in[7];
  const float* etim    = (const float*)d_in[8];
  const float* euid    = (const float*)d_in[9];
  const float* W_attn  = (const float*)d_in[10];
  const float* b_attn  = (const float*)d_in[11];
  const float* W_ih    = (const float*)d_in[12];
  const float* b_ih    = (const float*)d_in[13];
  const float* W_hh    = (const float*)d_in[14];
  const float* b_hh    = (const float*)d_in[15];
  const float* W_final = (const float*)d_in[16];
  const float* b_final = (const float*)d_in[17];
  float* out = (float*)d_out;
  char* ws = (char*)d_ws;

  // workspace layout (bytes)
  float* X     = (float*)(ws + 0ull);            // 8192*320*4   = 10,485,760
  float* gx    = (float*)(ws + 10485760ull);     // 8192*1536*4  = 50,331,648
  float* histf = (float*)(ws + 60817408ull);     // 16384*448*4  = 29,360,128
  float* histt = (float*)(ws + 90177536ull);     // 16384*512*4  = 33,554,432
  float* lastb = (float*)(ws + 123731968ull);    // 64*512*4
  float* ctx   = (float*)(ws + 123863040ull);    // 64*512*4
  float* yv    = (float*)(ws + 123994112ull);    // 64*5000*4 = 1,280,000
  short* h_bf  = (short*)(ws + 125274112ull);    // 2*64*512*2 = 131,072
  unsigned int* flags = (unsigned int*)(ws + 125405184ull);  // 4 grp x 16 x 64B = 4096

  gather_x<<<8192, 64, 0, stream>>>(loc, tim, eloc, etim, X);
  gemm_bt<false><<<dim3(12, 64), 256, 0, stream>>>(X, W_ih, b_ih, gx, 8192, 1536, 320);
  hist_feat<<<16384, 64, 0, stream>>>(hloc, htim, huid, eloc, etim, euid, histf);
  gemm_bt<true><<<dim3(4, 128), 256, 0, stream>>>(histf, W_attn, b_attn, histt, 16384, 512, 448);

  hipMemsetAsync(flags, 0, 4096, stream);
  gru_persist<<<64, 64, 0, stream>>>(gx, W_hh, b_hh, lens, h_bf, lastb, flags);

  attn_ctx<<<64, 256, 0, stream>>>(histt, lastb, ctx);
  final_gemm<<<625, 256, 0, stream>>>(lastb, ctx, W_final, b_final, yv);
  broadcast_y<<<8192, 256, 0, stream>>>(yv, out);
}

// Round 4
// 921.598 us; speedup vs baseline: 3.8248x; 1.1854x over previous
//
#include <hip/hip_runtime.h>
#include <hip/hip_bf16.h>

// Sizes (fixed): B=64 T=128 HID=512 LOC_EMB=256 TIM_EMB=64 UID_EMB=128
// L_HIST=1024 G=4, K_x=320, K_attn=448, N_gates=1536, UID_SIZE=5000

typedef __attribute__((ext_vector_type(8))) short bf16x8;
typedef __attribute__((ext_vector_type(4))) float f32x4;
typedef __attribute__((ext_vector_type(4))) unsigned short u16x4;
typedef __attribute__((ext_vector_type(2))) unsigned long long u64x2;
typedef unsigned long long u64;

__device__ inline unsigned short f2bf(float x) {
  __hip_bfloat16 b = __float2bfloat16(x);
  return __builtin_bit_cast(unsigned short, b);
}

// ---------------- gather x = [emb_loc[loc], emb_tim[tim]] -> X[(t*64+b)][320] ----------------
__global__ void gather_x(const int* __restrict__ loc, const int* __restrict__ tim,
                         const float* __restrict__ eloc, const float* __restrict__ etim,
                         float* __restrict__ X) {
  int row = blockIdx.x;            // t*64 + b
  int t = row >> 6, b = row & 63;
  int tid = threadIdx.x;           // 64 threads
  float4* dst = (float4*)(X + (size_t)row * 320);
  int li = loc[b * 128 + t];
  dst[tid] = ((const float4*)(eloc + (size_t)li * 256))[tid];
  if (tid < 16) {
    int ti = tim[b * 128 + t];
    dst[64 + tid] = ((const float4*)(etim + (size_t)ti * 64))[tid];
  }
}

// ---------------- hist features: [loc(256) | tim(64) | uid_mean(128)] per (b, n) ----------------
__global__ void hist_feat(const int* __restrict__ hloc, const int* __restrict__ htim,
                          const int* __restrict__ huid,
                          const float* __restrict__ eloc, const float* __restrict__ etim,
                          const float* __restrict__ euid, float* __restrict__ histf) {
  int row = blockIdx.x;            // b*256 + n
  int b = row >> 8, n = row & 255;
  int tid = threadIdx.x;           // 64 threads
  int base = b * 1024 + (n << 2);
  float4* dst = (float4*)(histf + (size_t)row * 448);
  {
    int li = hloc[base];
    dst[tid] = ((const float4*)(eloc + (size_t)li * 256))[tid];
  }
  if (tid < 16) {
    int ti = htim[base];
    dst[64 + tid] = ((const float4*)(etim + (size_t)ti * 64))[tid];
  }
  if (tid < 32) {
    const float4* u0 = (const float4*)(euid + (size_t)huid[base + 0] * 128);
    const float4* u1 = (const float4*)(euid + (size_t)huid[base + 1] * 128);
    const float4* u2 = (const float4*)(euid + (size_t)huid[base + 2] * 128);
    const float4* u3 = (const float4*)(euid + (size_t)huid[base + 3] * 128);
    float4 v0 = u0[tid], v1 = u1[tid], v2 = u2[tid], v3 = u3[tid];
    float4 o;
    o.x = 0.25f * (v0.x + v1.x + v2.x + v3.x);
    o.y = 0.25f * (v0.y + v1.y + v2.y + v3.y);
    o.z = 0.25f * (v0.z + v1.z + v2.z + v3.z);
    o.w = 0.25f * (v0.w + v1.w + v2.w + v3.w);
    dst[80 + tid] = o;
  }
}

// ---------------- fp32 tiled GEMM: C[m][n] = act(sum_k A[m][k]*B[n][k] + bias[n]) ----------------
template<bool TANH>
__global__ __launch_bounds__(256)
void gemm_bt(const float* __restrict__ A, const float* __restrict__ Bm,
             const float* __restrict__ bias, float* __restrict__ C,
             int M, int N, int K) {
  constexpr int BM = 128, BN = 128, BK = 16;
  __shared__ float As[BK][BM + 4];
  __shared__ float Bs[BK][BN + 4];
  const int tid = threadIdx.x;
  const int bm = blockIdx.y * BM, bn = blockIdx.x * BN;
  const int tm = (tid >> 4) << 3, tn = (tid & 15) << 3;
  const int lr = tid >> 2;
  const int lc = (tid & 3) << 2;
  const float* Ap0 = A + (size_t)(bm + lr) * K + lc;
  const float* Ap1 = A + (size_t)(bm + 64 + lr) * K + lc;
  const float* Bp0 = Bm + (size_t)(bn + lr) * K + lc;
  const float* Bp1 = Bm + (size_t)(bn + 64 + lr) * K + lc;
  float acc[8][8] = {};
  for (int k0 = 0; k0 < K; k0 += BK) {
    float4 a0 = *(const float4*)(Ap0 + k0);
    float4 a1 = *(const float4*)(Ap1 + k0);
    float4 b0 = *(const float4*)(Bp0 + k0);
    float4 b1 = *(const float4*)(Bp1 + k0);
    As[lc + 0][lr] = a0.x; As[lc + 1][lr] = a0.y; As[lc + 2][lr] = a0.z; As[lc + 3][lr] = a0.w;
    As[lc + 0][64 + lr] = a1.x; As[lc + 1][64 + lr] = a1.y; As[lc + 2][64 + lr] = a1.z; As[lc + 3][64 + lr] = a1.w;
    Bs[lc + 0][lr] = b0.x; Bs[lc + 1][lr] = b0.y; Bs[lc + 2][lr] = b0.z; Bs[lc + 3][lr] = b0.w;
    Bs[lc + 0][64 + lr] = b1.x; Bs[lc + 1][64 + lr] = b1.y; Bs[lc + 2][64 + lr] = b1.z; Bs[lc + 3][64 + lr] = b1.w;
    __syncthreads();
#pragma unroll
    for (int kk = 0; kk < BK; ++kk) {
      float a[8], bv[8];
      *(float4*)&a[0]  = *(const float4*)&As[kk][tm];
      *(float4*)&a[4]  = *(const float4*)&As[kk][tm + 4];
      *(float4*)&bv[0] = *(const float4*)&Bs[kk][tn];
      *(float4*)&bv[4] = *(const float4*)&Bs[kk][tn + 4];
#pragma unroll
      for (int i = 0; i < 8; ++i)
#pragma unroll
        for (int j = 0; j < 8; ++j)
          acc[i][j] += a[i] * bv[j];
    }
    __syncthreads();
  }
#pragma unroll
  for (int i = 0; i < 8; ++i) {
    float* crow = C + (size_t)(bm + tm + i) * N + bn + tn;
#pragma unroll
    for (int j = 0; j < 8; ++j) {
      float v = acc[i][j] + bias[bn + tn + j];
      if (TANH) v = tanhf(v);
      crow[j] = v;
    }
  }
}

// ---------------- persistent GRU: all 128 steps in one kernel ----------------
// 64 blocks x 64 threads (1 wave). block = (chunk c = bid>>2 in [0,16), group g = bid&3).
// Block owns j in [32c, 32c+32) and batches [16g, 16g+16).
// W_hh slice (3 gates x 32 rows x 512) in LDS as bf16 (96 KB), XOR-swizzled.
// h exchange: L3-direct (agent-scope sc1) relaxed atomics, NO fences.
//   producer: relaxed 8B atomic h stores -> s_waitcnt vmcnt(0) -> relaxed flag store
//   consumer: relaxed flag poll -> relaxed 8B atomic h loads (fresh from L3 by construction)
__global__ __launch_bounds__(64)
void gru_persist(const float* __restrict__ gx, const float* __restrict__ W_hh,
                 const float* __restrict__ b_hh, const int* __restrict__ lens,
                 short* __restrict__ h_bf, float* __restrict__ lastb,
                 unsigned int* __restrict__ flags) {
  __shared__ short wlds[6 * 16 * 512];   // 6 slabs (3 gates x 2 j-subtiles) x 16x512 bf16 = 96 KB
  const int lane = threadIdx.x;
  const int bid = blockIdx.x;
  const int c = bid >> 2, grp = bid & 3;
  const int j0 = c << 5;                 // 32 j rows
  const int b0 = grp << 4;               // 16 batches
  const int m16 = lane & 15, g4 = lane >> 4;

  // ---- load weight slice into LDS (once), fp32 -> bf16, swizzled ----
  for (int s = 0; s < 6; ++s) {          // s = g*2 + tt
    int g = s >> 1, tt = s & 1;
    const float* wg = W_hh + (size_t)(g * 512 + j0 + tt * 16) * 512;
    for (int r = 0; r < 16; ++r) {
      int k = lane << 3;
      const float4* src = (const float4*)(wg + (size_t)r * 512 + k);
      float4 f0 = src[0], f1 = src[1];
      bf16x8 w;
      w[0] = (short)f2bf(f0.x); w[1] = (short)f2bf(f0.y);
      w[2] = (short)f2bf(f0.z); w[3] = (short)f2bf(f0.w);
      w[4] = (short)f2bf(f1.x); w[5] = (short)f2bf(f1.y);
      w[6] = (short)f2bf(f1.z); w[7] = (short)f2bf(f1.w);
      int off = ((r << 9) + k) ^ ((r & 7) << 3);   // short units
      *(bf16x8*)(wlds + (s << 13) + off) = w;
    }
  }

  // ---- per-lane constants ----
  const int bcol = b0 + m16;             // this lane's batch
  const int jr0 = j0 + (g4 << 2);        // j rows for tt=0
  const int jr1 = jr0 + 16;              // j rows for tt=1
  const f32x4 bhr0 = *(const f32x4*)&b_hh[jr0];
  const f32x4 bhz0 = *(const f32x4*)&b_hh[512 + jr0];
  const f32x4 bhn0 = *(const f32x4*)&b_hh[1024 + jr0];
  const f32x4 bhr1 = *(const f32x4*)&b_hh[jr1];
  const f32x4 bhz1 = *(const f32x4*)&b_hh[512 + jr1];
  const f32x4 bhn1 = *(const f32x4*)&b_hh[1024 + jr1];
  const int lenb = lens[bcol];
  f32x4 hprev0 = {0.f, 0.f, 0.f, 0.f}, hprev1 = {0.f, 0.f, 0.f, 0.f};

  unsigned int* gflags = flags + (grp << 8);       // 16 flags x 16 dwords (64B) apart
  unsigned int* ownflag = gflags + (c << 4);

  for (int t = 0; t < 128; ++t) {
    // gx loads first: independent of h, latency hides under the flag wait
    const float* gxb = gx + ((size_t)t * 64 + bcol) * 1536;
    f32x4 gr0 = *(const f32x4*)(gxb + jr0);
    f32x4 gz0 = *(const f32x4*)(gxb + 512 + jr0);
    f32x4 gn0 = *(const f32x4*)(gxb + 1024 + jr0);
    f32x4 gr1 = *(const f32x4*)(gxb + jr1);
    f32x4 gz1 = *(const f32x4*)(gxb + 512 + jr1);
    f32x4 gn1 = *(const f32x4*)(gxb + 1024 + jr1);

    f32x4 ar0 = {0.f, 0.f, 0.f, 0.f}, az0 = ar0, an0 = ar0;
    f32x4 ar1 = ar0, az1 = ar0, an1 = ar0;
    if (t) {
      // wait: all 16 chunk-blocks of this group finished step t-1 (relaxed poll, no fence)
      unsigned tgt = (unsigned)t;
      while (true) {
        unsigned f = tgt;
        if (lane < 16)
          f = __hip_atomic_load(gflags + (lane << 4), __ATOMIC_RELAXED, __HIP_MEMORY_SCOPE_AGENT);
        if (__all((int)(f >= tgt))) break;
      }
      asm volatile("" ::: "memory");   // compile-time ordering only

      // h loads: L3-direct atomics, fresh by construction (flag was stored after vmcnt(0))
      const u64* hp = (const u64*)(h_bf + ((t & 1) << 15) + (size_t)bcol * 512 + (g4 << 3));
      u64 hu[32];
#pragma unroll
      for (int ks = 0; ks < 16; ++ks) {
        hu[2 * ks]     = __hip_atomic_load(hp + ks * 8,     __ATOMIC_RELAXED, __HIP_MEMORY_SCOPE_AGENT);
        hu[2 * ks + 1] = __hip_atomic_load(hp + ks * 8 + 1, __ATOMIC_RELAXED, __HIP_MEMORY_SCOPE_AGENT);
      }
#define GRU_MFMA(ks)                                                                \
      {                                                                             \
        u64x2 p; p[0] = hu[2 * ks]; p[1] = hu[2 * ks + 1];                          \
        bf16x8 hf = __builtin_bit_cast(bf16x8, p);                                  \
        int off = ((m16 << 9) + (ks << 5) + (g4 << 3)) ^ ((m16 & 7) << 3);          \
        ar0 = __builtin_amdgcn_mfma_f32_16x16x32_bf16(*(const bf16x8*)(wlds + off), hf, ar0, 0, 0, 0);              \
        ar1 = __builtin_amdgcn_mfma_f32_16x16x32_bf16(*(const bf16x8*)(wlds + 8192 + off), hf, ar1, 0, 0, 0);       \
        az0 = __builtin_amdgcn_mfma_f32_16x16x32_bf16(*(const bf16x8*)(wlds + 16384 + off), hf, az0, 0, 0, 0);      \
        az1 = __builtin_amdgcn_mfma_f32_16x16x32_bf16(*(const bf16x8*)(wlds + 24576 + off), hf, az1, 0, 0, 0);      \
        an0 = __builtin_amdgcn_mfma_f32_16x16x32_bf16(*(const bf16x8*)(wlds + 32768 + off), hf, an0, 0, 0, 0);      \
        an1 = __builtin_amdgcn_mfma_f32_16x16x32_bf16(*(const bf16x8*)(wlds + 40960 + off), hf, an1, 0, 0, 0);      \
      }
      GRU_MFMA(0)  GRU_MFMA(1)  GRU_MFMA(2)  GRU_MFMA(3)
      GRU_MFMA(4)  GRU_MFMA(5)  GRU_MFMA(6)  GRU_MFMA(7)
      GRU_MFMA(8)  GRU_MFMA(9)  GRU_MFMA(10) GRU_MFMA(11)
      GRU_MFMA(12) GRU_MFMA(13) GRU_MFMA(14) GRU_MFMA(15)
#undef GRU_MFMA
    }
    u16x4 hw0, hw1;
#pragma unroll
    for (int q = 0; q < 4; ++q) {
      float r = 1.f / (1.f + expf(-(gr0[q] + ar0[q] + bhr0[q])));
      float z = 1.f / (1.f + expf(-(gz0[q] + az0[q] + bhz0[q])));
      float n = tanhf(gn0[q] + r * (an0[q] + bhn0[q]));
      float hv = (1.f - z) * n + z * hprev0[q];
      hprev0[q] = hv;
      hw0[q] = f2bf(hv);
    }
#pragma unroll
    for (int q = 0; q < 4; ++q) {
      float r = 1.f / (1.f + expf(-(gr1[q] + ar1[q] + bhr1[q])));
      float z = 1.f / (1.f + expf(-(gz1[q] + az1[q] + bhz1[q])));
      float n = tanhf(gn1[q] + r * (an1[q] + bhn1[q]));
      float hv = (1.f - z) * n + z * hprev1[q];
      hprev1[q] = hv;
      hw1[q] = f2bf(hv);
    }
    short* hbws = h_bf + ((~t & 1) << 15) + (size_t)bcol * 512;
    __hip_atomic_store((u64*)(hbws + jr0), __builtin_bit_cast(u64, hw0),
                       __ATOMIC_RELAXED, __HIP_MEMORY_SCOPE_AGENT);
    __hip_atomic_store((u64*)(hbws + jr1), __builtin_bit_cast(u64, hw1),
                       __ATOMIC_RELAXED, __HIP_MEMORY_SCOPE_AGENT);
    if (t == lenb - 1) {
      *(f32x4*)(lastb + (size_t)bcol * 512 + jr0) = hprev0;
      *(f32x4*)(lastb + (size_t)bcol * 512 + jr1) = hprev1;
    }
    if (t < 127) {
      asm volatile("s_waitcnt vmcnt(0)" ::: "memory");   // h stores acked at coherence point
      if (lane == 0)
        __hip_atomic_store(ownflag, (unsigned)(t + 1), __ATOMIC_RELAXED, __HIP_MEMORY_SCOPE_AGENT);
    }
  }
}

// ---------------- attention: energies, softmax, context (one block per b) ----------------
__global__ __launch_bounds__(256)
void attn_ctx(const float* __restrict__ histt, const float* __restrict__ last,
              float* __restrict__ ctx) {
  int b = blockIdx.x, tid = threadIdx.x;
  __shared__ float ls[512];
  __shared__ float w[256];
  __shared__ float red[256];
  ((float2*)ls)[tid] = ((const float2*)(last + (size_t)b * 512))[tid];
  __syncthreads();
  const float* hb = histt + (size_t)b * 256 * 512;
  const float* hrow = hb + (size_t)tid * 512;
  float acc = 0.f;
  for (int k = 0; k < 512; k += 4) {
    float4 h4 = *(const float4*)(hrow + k);
    acc += ls[k] * h4.x + ls[k + 1] * h4.y + ls[k + 2] * h4.z + ls[k + 3] * h4.w;
  }
  red[tid] = acc;
  __syncthreads();
  for (int s = 128; s; s >>= 1) {
    if (tid < s) red[tid] = fmaxf(red[tid], red[tid + s]);
    __syncthreads();
  }
  float m = red[0];
  __syncthreads();
  float ex = expf(acc - m);
  w[tid] = ex; red[tid] = ex;
  __syncthreads();
  for (int s = 128; s; s >>= 1) {
    if (tid < s) red[tid] += red[tid + s];
    __syncthreads();
  }
  float inv = 1.f / red[0];
  float c0 = 0.f, c1 = 0.f;
  for (int n = 0; n < 256; ++n) {
    float wn = w[n];
    c0 += wn * hb[(size_t)n * 512 + tid];
    c1 += wn * hb[(size_t)n * 512 + tid + 256];
  }
  ctx[(size_t)b * 512 + tid]       = c0 * inv;
  ctx[(size_t)b * 512 + tid + 256] = c1 * inv;
}

// ---------------- final: y[b][u] = [last|ctx|last] . W_final[u] + b_final[u] ----------------
__global__ __launch_bounds__(256)
void final_gemm(const float* __restrict__ last, const float* __restrict__ ctx,
                const float* __restrict__ Wf, const float* __restrict__ bf,
                float* __restrict__ y) {
  __shared__ float s[64][129];
  const int tid = threadIdx.x;
  const int u0 = blockIdx.x << 3;
  const int ul = tid >> 6, b = tid & 63;
  float acc0 = 0.f, acc1 = 0.f;
  for (int kc = 0; kc < 12; ++kc) {
    __syncthreads();
    for (int i = tid; i < 2048; i += 256) {
      int rb = i >> 5, cc = (i & 31) << 2;
      int k = kc * 128 + cc;
      const float* src = (k < 512) ? (last + (size_t)rb * 512 + k)
                       : (k < 1024) ? (ctx + (size_t)rb * 512 + k - 512)
                                    : (last + (size_t)rb * 512 + k - 1024);
      float4 v = *(const float4*)src;
      s[rb][cc] = v.x; s[rb][cc + 1] = v.y; s[rb][cc + 2] = v.z; s[rb][cc + 3] = v.w;
    }
    __syncthreads();
#pragma unroll
    for (int uu = 0; uu < 2; ++uu) {
      int u = u0 + ul + uu * 4;
      const float* wrow = Wf + (size_t)u * 1536 + kc * 128;
      float a = 0.f;
#pragma unroll 8
      for (int c = 0; c < 128; c += 4) {
        float4 w4 = *(const float4*)(wrow + c);
        a += w4.x * s[b][c] + w4.y * s[b][c + 1] + w4.z * s[b][c + 2] + w4.w * s[b][c + 3];
      }
      if (uu == 0) acc0 += a; else acc1 += a;
    }
  }
  int u = u0 + ul;
  y[(size_t)b * 5000 + u]     = acc0 + bf[u];
  y[(size_t)b * 5000 + u + 4] = acc1 + bf[u + 4];
}

// ---------------- broadcast y (B,5000) -> out (B,T,5000) ----------------
__global__ void broadcast_y(const float* __restrict__ y, float* __restrict__ out) {
  int bt = blockIdx.x;
  const float4* src = (const float4*)(y + (size_t)(bt >> 7) * 5000);
  float4* dst = (float4*)(out + (size_t)bt * 5000);
  for (int i = threadIdx.x; i < 1250; i += 256) dst[i] = src[i];
}

extern "C" void kernel_launch(void* const* d_in, const int* in_sizes, int n_in,
                              void* d_out, int out_size, void* d_ws, size_t ws_size,
                              hipStream_t stream) {
  const int* loc  = (const int*)d_in[0];
  const int* tim  = (const int*)d_in[1];
  const int* lens = (const int*)d_in[2];
  const int* hloc = (const int*)d_in[3];
  const int* htim = (const int*)d_in[4];
  const int* huid = (const int*)d_in[5];
  // d_in[6] = group_size (constant 4, baked in)
  const float* eloc    = (const float*)d_in[7];
  const float* etim    = (const float*)d_in[8];
  const float* euid    = (const float*)d_in[9];
  const float* W_attn  = (const float*)d_in[10];
  const float* b_attn  = (const float*)d_in[11];
  const float* W_ih    = (const float*)d_in[12];
  const float* b_ih    = (const float*)d_in[13];
  const float* W_hh    = (const float*)d_in[14];
  const float* b_hh    = (const float*)d_in[15];
  const float* W_final = (const float*)d_in[16];
  const float* b_final = (const float*)d_in[17];
  float* out = (float*)d_out;
  char* ws = (char*)d_ws;

  // workspace layout (bytes)
  float* X     = (float*)(ws + 0ull);            // 8192*320*4   = 10,485,760
  float* gx    = (float*)(ws + 10485760ull);     // 8192*1536*4  = 50,331,648
  float* histf = (float*)(ws + 60817408ull);     // 16384*448*4  = 29,360,128
  float* histt = (float*)(ws + 90177536ull);     // 16384*512*4  = 33,554,432
  float* lastb = (float*)(ws + 123731968ull);    // 64*512*4
  float* ctx   = (float*)(ws + 123863040ull);    // 64*512*4
  float* yv    = (float*)(ws + 123994112ull);    // 64*5000*4 = 1,280,000
  short* h_bf  = (short*)(ws + 125274112ull);    // 2*64*512*2 = 131,072
  unsigned int* flags = (unsigned int*)(ws + 125405184ull);  // 4 grp x 16 x 64B = 4096

  gather_x<<<8192, 64, 0, stream>>>(loc, tim, eloc, etim, X);
  gemm_bt<false><<<dim3(12, 64), 256, 0, stream>>>(X, W_ih, b_ih, gx, 8192, 1536, 320);
  hist_feat<<<16384, 64, 0, stream>>>(hloc, htim, huid, eloc, etim, euid, histf);
  gemm_bt<true><<<dim3(4, 128), 256, 0, stream>>>(histf, W_attn, b_attn, histt, 16384, 512, 448);

  hipMemsetAsync(flags, 0, 4096, stream);
  gru_persist<<<64, 64, 0, stream>>>(gx, W_hh, b_hh, lens, h_bf, lastb, flags);

  attn_ctx<<<64, 256, 0, stream>>>(histt, lastb, ctx);
  final_gemm<<<625, 256, 0, stream>>>(lastb, ctx, W_final, b_final, yv);
  broadcast_y<<<8192, 256, 0, stream>>>(yv, out);
}